// Round 2
// baseline (140.996 us; speedup 1.0000x reference)
//
#include <hip/hip_runtime.h>
#include <math.h>

#define B 1024
#define O 256
#define D 1024
#define ALPHA 0.005f

#define BPB 4            // b rows per block
#define CH  32           // d chunk (floats) held in registers per buffer
#define NCH (D / CH)     // 32 chunks
#define QF  (CH / 4)     // 8 float4 per chunk

// One fused kernel:
//   lane -> centroid o (tid 0..255), block -> 4 consecutive b rows.
//   x[b][d] is wave-uniform (scalar-load / broadcast), c[o][chunk] lives in
//   VGPRs, double-buffered. No LDS in the hot loop; alpha row-reduction fused.
__global__ __launch_bounds__(256) void fused_kernel(const float* __restrict__ x,
                                                    const float* __restrict__ c,
                                                    float* __restrict__ out)
{
    const int o  = threadIdx.x;          // centroid index, 0..255
    const int b0 = blockIdx.x * BPB;     // first b row of this block

    const float* crow = c + (size_t)o * D;

    float s1[BPB], s2[BPB];
    #pragma unroll
    for (int i = 0; i < BPB; ++i) { s1[i] = 0.f; s2[i] = 0.f; }

    float4 bufA[QF], bufB[QF];

    #pragma unroll
    for (int q = 0; q < QF; ++q) bufA[q] = ((const float4*)crow)[q];

#define COMPUTE(BUF, CHIDX)                                                         \
    {                                                                               \
        const float* xb = x + (size_t)b0 * D + (size_t)(CHIDX) * CH;                \
        _Pragma("unroll")                                                           \
        for (int bi = 0; bi < BPB; ++bi) {                                          \
            _Pragma("unroll")                                                       \
            for (int q = 0; q < QF; ++q) {                                          \
                float4 xv = ((const float4*)(xb + bi * D))[q];                      \
                float4 cv = BUF[q];                                                 \
                float d0 = xv.x - cv.x, d1 = xv.y - cv.y,                           \
                      d2 = xv.z - cv.z, d3 = xv.w - cv.w;                           \
                s1[bi] += __builtin_fabsf(d0); s2[bi] = __builtin_fmaf(d0, d0, s2[bi]); \
                s1[bi] += __builtin_fabsf(d1); s2[bi] = __builtin_fmaf(d1, d1, s2[bi]); \
                s1[bi] += __builtin_fabsf(d2); s2[bi] = __builtin_fmaf(d2, d2, s2[bi]); \
                s1[bi] += __builtin_fabsf(d3); s2[bi] = __builtin_fmaf(d3, d3, s2[bi]); \
            }                                                                       \
        }                                                                           \
    }

    for (int ch = 0; ch < NCH; ch += 2) {
        // prefetch chunk ch+1 into B while computing with A(ch)
        #pragma unroll
        for (int q = 0; q < QF; ++q)
            bufB[q] = ((const float4*)(crow + (size_t)(ch + 1) * CH))[q];
        COMPUTE(bufA, ch);

        // prefetch chunk ch+2 into A (clamped; redundant last load is harmless
        // and stays in-bounds) while computing with B(ch+1)
        const int nch = (ch + 2 < NCH) ? (ch + 2) : (NCH - 1);
        #pragma unroll
        for (int q = 0; q < QF; ++q)
            bufA[q] = ((const float4*)(crow + (size_t)nch * CH))[q];
        COMPUTE(bufB, ch + 1);
    }
#undef COMPUTE

    // v = d1/T0 + d2/T1 = s1 + 0.5*sqrt(s2)
    float v[BPB], r[BPB];
    #pragma unroll
    for (int i = 0; i < BPB; ++i)
        v[i] = s1[i] + 0.5f * __builtin_sqrtf(s2[i]);

    // alpha correction: S[b] = sum_o v[b][o] over all 256 o in this block
    __shared__ float red[4][BPB];
    #pragma unroll
    for (int i = 0; i < BPB; ++i) {
        float t = v[i];
        #pragma unroll
        for (int off = 32; off >= 1; off >>= 1)
            t += __shfl_down(t, off, 64);
        r[i] = t;                        // lane 0 of each wave holds wave sum
    }
    const int lane = o & 63;
    const int wv   = o >> 6;
    if (lane == 0) {
        #pragma unroll
        for (int i = 0; i < BPB; ++i) red[wv][i] = r[i];
    }
    __syncthreads();
    #pragma unroll
    for (int i = 0; i < BPB; ++i) {
        const float S = red[0][i] + red[1][i] + red[2][i] + red[3][i];
        out[(size_t)(b0 + i) * O + o] = ALPHA * S - (1.0f + ALPHA) * v[i];
    }
}

extern "C" void kernel_launch(void* const* d_in, const int* in_sizes, int n_in,
                              void* d_out, int out_size, void* d_ws, size_t ws_size,
                              hipStream_t stream) {
    const float* x = (const float*)d_in[0];   // [B, D]
    const float* c = (const float*)d_in[1];   // [O, D]
    float* out = (float*)d_out;               // [B, O]

    fused_kernel<<<B / BPB, O, 0, stream>>>(x, c, out);  // 256 blocks x 256 thr
}

// Round 3
// 96.375 us; speedup vs baseline: 1.4630x; 1.4630x over previous
//
#include <hip/hip_runtime.h>
#include <math.h>

#define B 1024
#define O 256
#define D 1024
#define ALPHA 0.005f

#define BPB 4            // b rows per block
#define DS  4            // D splits (blockIdx.y)
#define DCH (D / DS)     // 256 d per block
#define CH  32           // d chunk (floats) per register buffer
#define NCH (DCH / CH)   // 8 chunks per block
#define QF  (CH / 4)     // 8 float4 per chunk

// Kernel 1: partial sums over a D-slice.
//   lane -> centroid o (tid 0..255), blockIdx.x -> 4 b rows, blockIdx.y -> d-slice.
//   x[b][d] is wave-uniform (broadcast load), c[o][chunk] double-buffered in VGPRs.
//   1024 blocks -> ~3 blocks/CU so x-load latency is hidden by TLP.
__global__ __launch_bounds__(256, 3) void dist_part(const float* __restrict__ x,
                                                    const float* __restrict__ c,
                                                    float* __restrict__ s1p,
                                                    float* __restrict__ s2p)
{
    const int o  = threadIdx.x;               // centroid index
    const int b0 = blockIdx.x * BPB;          // first b row
    const int ds = blockIdx.y;                // d-slice index
    const int dbase = ds * DCH;

    const float* crow = c + (size_t)o * D + dbase;
    const float* xrow = x + (size_t)b0 * D + dbase;

    float s1[BPB], s2[BPB];
    #pragma unroll
    for (int i = 0; i < BPB; ++i) { s1[i] = 0.f; s2[i] = 0.f; }

    float4 bufA[QF], bufB[QF];
    #pragma unroll
    for (int q = 0; q < QF; ++q) bufA[q] = ((const float4*)crow)[q];

#define COMPUTE(BUF, CHIDX)                                                         \
    {                                                                               \
        const float* xb = xrow + (size_t)(CHIDX) * CH;                              \
        _Pragma("unroll")                                                           \
        for (int bi = 0; bi < BPB; ++bi) {                                          \
            _Pragma("unroll")                                                       \
            for (int q = 0; q < QF; ++q) {                                          \
                float4 xv = ((const float4*)(xb + (size_t)bi * D))[q];              \
                float4 cv = BUF[q];                                                 \
                float d0 = xv.x - cv.x, d1 = xv.y - cv.y,                           \
                      d2 = xv.z - cv.z, d3 = xv.w - cv.w;                           \
                s1[bi] += __builtin_fabsf(d0); s2[bi] = __builtin_fmaf(d0, d0, s2[bi]); \
                s1[bi] += __builtin_fabsf(d1); s2[bi] = __builtin_fmaf(d1, d1, s2[bi]); \
                s1[bi] += __builtin_fabsf(d2); s2[bi] = __builtin_fmaf(d2, d2, s2[bi]); \
                s1[bi] += __builtin_fabsf(d3); s2[bi] = __builtin_fmaf(d3, d3, s2[bi]); \
            }                                                                       \
        }                                                                           \
    }

    for (int ch = 0; ch < NCH; ch += 2) {
        #pragma unroll
        for (int q = 0; q < QF; ++q)
            bufB[q] = ((const float4*)(crow + (size_t)(ch + 1) * CH))[q];
        COMPUTE(bufA, ch);

        const int nch = (ch + 2 < NCH) ? (ch + 2) : (NCH - 1);
        #pragma unroll
        for (int q = 0; q < QF; ++q)
            bufA[q] = ((const float4*)(crow + (size_t)nch * CH))[q];
        COMPUTE(bufB, ch + 1);
    }
#undef COMPUTE

    #pragma unroll
    for (int i = 0; i < BPB; ++i) {
        const size_t idx = ((size_t)ds * B + (b0 + i)) * O + o;
        s1p[idx] = s1[i];
        s2p[idx] = s2[i];
    }
}

// Kernel 2: combine D-slices, apply sqrt + temperature + alpha row-correction.
__global__ __launch_bounds__(256) void combine_kernel(const float* __restrict__ s1p,
                                                      const float* __restrict__ s2p,
                                                      float* __restrict__ out)
{
    const int b = blockIdx.x;
    const int o = threadIdx.x;

    float a1 = 0.f, a2 = 0.f;
    #pragma unroll
    for (int ds = 0; ds < DS; ++ds) {
        const size_t idx = ((size_t)ds * B + b) * O + o;
        a1 += s1p[idx];
        a2 += s2p[idx];
    }
    const float v = a1 + 0.5f * __builtin_sqrtf(a2);

    // row sum over 256 o
    float t = v;
    #pragma unroll
    for (int off = 32; off >= 1; off >>= 1)
        t += __shfl_down(t, off, 64);

    __shared__ float ws[4];
    if ((o & 63) == 0) ws[o >> 6] = t;
    __syncthreads();
    const float S = ws[0] + ws[1] + ws[2] + ws[3];

    out[(size_t)b * O + o] = ALPHA * S - (1.0f + ALPHA) * v;
}

extern "C" void kernel_launch(void* const* d_in, const int* in_sizes, int n_in,
                              void* d_out, int out_size, void* d_ws, size_t ws_size,
                              hipStream_t stream) {
    const float* x = (const float*)d_in[0];   // [B, D]
    const float* c = (const float*)d_in[1];   // [O, D]
    float* out = (float*)d_out;               // [B, O]

    float* s1p = (float*)d_ws;                          // [DS, B, O] = 4 MB
    float* s2p = s1p + (size_t)DS * B * O;              // [DS, B, O] = 4 MB

    dim3 grid(B / BPB, DS);                   // (256, 4) = 1024 blocks
    dist_part<<<grid, 256, 0, stream>>>(x, c, s1p, s2p);
    combine_kernel<<<B, 256, 0, stream>>>(s1p, s2p, out);
}

// Round 4
// 89.006 us; speedup vs baseline: 1.5841x; 1.0828x over previous
//
#include <hip/hip_runtime.h>
#include <math.h>

#define B 1024
#define O 256
#define D 1024
#define ALPHA 0.005f

#define BPB 4            // b rows per block
#define DS  4            // D splits (blockIdx.y)
#define DCH (D / DS)     // 256 d per block
#define CH  8            // d chunk per register buffer
#define NCH (DCH / CH)   // 32 chunks
#define CQ  (CH / 4)     // 2 float4 per chunk (c)
 
// Kernel 0: transpose c[O][D] -> ct[D/4][O] (float4 elements)
// block = one d4-row group, tid = o  -> writes coalesced.
__global__ __launch_bounds__(256) void transpose_c(const float* __restrict__ c,
                                                   float4* __restrict__ ct)
{
    const int o  = threadIdx.x;         // 0..255
    const int d4 = blockIdx.x;          // 0..D/4-1
    const float* src = c + (size_t)o * D + d4 * 4;
    ct[(size_t)d4 * O + o] = make_float4(src[0], src[1], src[2], src[3]);
}

// Kernel 1: partial sums over a D-slice.
// lane -> centroid o; blockIdx.x -> 4 b rows; blockIdx.y -> d-slice.
// x[b][d] wave-uniform broadcast loads; c coalesced via ct.
// Both x and c explicitly double-buffered: loads for chunk k+1 issue before
// compute of chunk k, so the waitcnt lands after a full compute window.
__global__ __launch_bounds__(256) void dist_part(const float* __restrict__ x,
                                                 const float4* __restrict__ ct,
                                                 float* __restrict__ s1p,
                                                 float* __restrict__ s2p)
{
    const int o  = threadIdx.x;               // centroid index
    const int b0 = blockIdx.x * BPB;          // first b row
    const int ds = blockIdx.y;                // d-slice
    const int d4base = ds * (DCH / 4);        // base float4-index into ct rows

    const float4* xrow = (const float4*)(x + (size_t)b0 * D) + d4base; // row stride D/4
    const float4* cts  = ct + (size_t)d4base * O + o;                  // step O per d4

    float s1[BPB], s2[BPB];
    #pragma unroll
    for (int i = 0; i < BPB; ++i) { s1[i] = 0.f; s2[i] = 0.f; }

    float4 cA[CQ], cB[CQ];
    float4 xA[BPB][CQ], xB[BPB][CQ];

#define LOADC(BUF, CHIDX)                                                   \
    { _Pragma("unroll")                                                     \
      for (int j = 0; j < CQ; ++j)                                          \
          BUF[j] = cts[((size_t)(CHIDX) * CQ + j) * O]; }

#define LOADX(BUF, CHIDX)                                                   \
    { _Pragma("unroll")                                                     \
      for (int bi = 0; bi < BPB; ++bi)                                      \
          _Pragma("unroll")                                                 \
          for (int j = 0; j < CQ; ++j)                                      \
              BUF[bi][j] = xrow[(size_t)bi * (D / 4) + (CHIDX) * CQ + j]; }

#define COMPUTE(CBUF, XBUF)                                                 \
    { _Pragma("unroll")                                                     \
      for (int bi = 0; bi < BPB; ++bi) {                                    \
          _Pragma("unroll")                                                 \
          for (int j = 0; j < CQ; ++j) {                                    \
              float4 xv = XBUF[bi][j];                                      \
              float4 cv = CBUF[j];                                          \
              float d0 = xv.x - cv.x, d1 = xv.y - cv.y,                     \
                    d2 = xv.z - cv.z, d3 = xv.w - cv.w;                     \
              s1[bi] += __builtin_fabsf(d0); s2[bi] = __builtin_fmaf(d0, d0, s2[bi]); \
              s1[bi] += __builtin_fabsf(d1); s2[bi] = __builtin_fmaf(d1, d1, s2[bi]); \
              s1[bi] += __builtin_fabsf(d2); s2[bi] = __builtin_fmaf(d2, d2, s2[bi]); \
              s1[bi] += __builtin_fabsf(d3); s2[bi] = __builtin_fmaf(d3, d3, s2[bi]); \
          }                                                                 \
      } }

    LOADC(cA, 0)
    LOADX(xA, 0)

    for (int ch = 0; ch < NCH; ch += 2) {
        LOADC(cB, ch + 1)
        LOADX(xB, ch + 1)
        COMPUTE(cA, xA)

        const int nch = (ch + 2 < NCH) ? (ch + 2) : (NCH - 1);
        LOADC(cA, nch)
        LOADX(xA, nch)
        COMPUTE(cB, xB)
    }
#undef LOADC
#undef LOADX
#undef COMPUTE

    #pragma unroll
    for (int i = 0; i < BPB; ++i) {
        const size_t idx = ((size_t)ds * B + (b0 + i)) * O + o;
        s1p[idx] = s1[i];
        s2p[idx] = s2[i];
    }
}

// Kernel 2: combine D-slices, sqrt + temperature + alpha row-correction.
__global__ __launch_bounds__(256) void combine_kernel(const float* __restrict__ s1p,
                                                      const float* __restrict__ s2p,
                                                      float* __restrict__ out)
{
    const int b = blockIdx.x;
    const int o = threadIdx.x;

    float a1 = 0.f, a2 = 0.f;
    #pragma unroll
    for (int ds = 0; ds < DS; ++ds) {
        const size_t idx = ((size_t)ds * B + b) * O + o;
        a1 += s1p[idx];
        a2 += s2p[idx];
    }
    const float v = a1 + 0.5f * __builtin_sqrtf(a2);

    float t = v;
    #pragma unroll
    for (int off = 32; off >= 1; off >>= 1)
        t += __shfl_down(t, off, 64);

    __shared__ float ws[4];
    if ((o & 63) == 0) ws[o >> 6] = t;
    __syncthreads();
    const float S = ws[0] + ws[1] + ws[2] + ws[3];

    out[(size_t)b * O + o] = ALPHA * S - (1.0f + ALPHA) * v;
}

extern "C" void kernel_launch(void* const* d_in, const int* in_sizes, int n_in,
                              void* d_out, int out_size, void* d_ws, size_t ws_size,
                              hipStream_t stream) {
    const float* x = (const float*)d_in[0];   // [B, D]
    const float* c = (const float*)d_in[1];   // [O, D]
    float* out = (float*)d_out;               // [B, O]

    float*  s1p = (float*)d_ws;                          // [DS, B, O] = 4 MB
    float*  s2p = s1p + (size_t)DS * B * O;              // [DS, B, O] = 4 MB
    float4* ct  = (float4*)(s2p + (size_t)DS * B * O);   // [D/4, O]   = 1 MB

    transpose_c<<<D / 4, O, 0, stream>>>(c, ct);

    dim3 grid(B / BPB, DS);                   // (256, 4) = 1024 blocks
    dist_part<<<grid, 256, 0, stream>>>(x, ct, s1p, s2p);
    combine_kernel<<<B, 256, 0, stream>>>(s1p, s2p, out);
}